// Round 1
// baseline (264.791 us; speedup 1.0000x reference)
//
#include <hip/hip_runtime.h>
#include <hip/hip_bf16.h>

// DigitCaps dynamic routing. Output fp32.
// R14: slimming pass.
//  - xB: x pre-converted to bf16 ONCE (prep kernel); sgemm + aggemm A-paths
//    read bf16 directly (no per-iteration f2bf, half the A bytes).
//  - agreement bij accumulated by atomicAdd straight into cumulative bijT
//    (u_part buffer + 33MB/block-redundant routebuild reduction deleted).
//  - softmax stats (sum of exp per o; max-subtract dropped, |bij| ~ O(1))
//    computed by the LAST aggemm block (atomic counter + threadfence).
//  - routebuildN is now a pure Bs build: exp(bij)*inv from global, no LDS.
#define B 512
#define IC 1152
#define QD 8
#define OD 10
#define PD 16
#define KD (IC * QD)       // 9216
#define NKB (KD / 32)      // 288 K32 blocks
#define NCS 72             // K-chunks for s GEMM; 288/72 = 4 K-steps
#define KSTEPS (NKB / NCS)
#define NCB 4              // b-chunks for agreement GEMM (128 each)
#define SOP (B * OD * PD)  // 81920
#define IO (IC * OD)       // 11520
#define XE (B * KD)        // 4718592 x elements
#define PREPX (XE / 8 / 256)  // 2304 blocks for xB build

typedef short bf16x8 __attribute__((ext_vector_type(8)));
typedef short bf16x4 __attribute__((ext_vector_type(4)));
typedef float f32x4 __attribute__((ext_vector_type(4)));

__device__ __forceinline__ short f2bf(float f) {
  union { float f; unsigned u; } x;
  x.f = f;
  unsigned r = x.u + 0x7FFFu + ((x.u >> 16) & 1u);  // RNE to bf16
  return (short)(r >> 16);
}

// ---------------- prep: xB build (blocks 0..2303) + Bs build mode0 ----------
__global__ __launch_bounds__(256) void prep_kernel(const float* __restrict__ x,
                                                   const float* __restrict__ W,
                                                   float* __restrict__ bijT,
                                                   int* __restrict__ ctr,
                                                   short* __restrict__ Bs,
                                                   short* __restrict__ xB) {
  const int bid = blockIdx.x, tid = threadIdx.x;
  if (bid < PREPX) {
    const size_t e0 = (((size_t)bid << 8) + tid) * 8;
    const float4 a = *(const float4*)(x + e0);
    const float4 b = *(const float4*)(x + e0 + 4);
    short ov[8];
    ov[0] = f2bf(a.x); ov[1] = f2bf(a.y); ov[2] = f2bf(a.z); ov[3] = f2bf(a.w);
    ov[4] = f2bf(b.x); ov[5] = f2bf(b.y); ov[6] = f2bf(b.z); ov[7] = f2bf(b.w);
    *(int4*)(xB + e0) = *(const int4*)ov;
    return;
  }
  const int t = (bid - PREPX) * 256 + tid;  // 0..46079
  if (t < IO) bijT[t] = 0.f;                // cumulative bij zero-init
  if (t == 0) *ctr = 0;
  const int kb = t / 160, n = t % 160;
  const int o = n >> 4, p = n & 15;
  const float ci = 1.0f / (float)IC;        // softmax(0) uniform
  short ov[32];
#pragma unroll
  for (int quad = 0; quad < 4; ++quad) {
    const int i = kb * 4 + quad;
    const float4* wp = (const float4*)(W + (((size_t)i * OD + o) * PD + p) * QD);
    const float4 w0 = wp[0], w1 = wp[1];
    ov[quad * 8 + 0] = f2bf(ci * w0.x); ov[quad * 8 + 1] = f2bf(ci * w0.y);
    ov[quad * 8 + 2] = f2bf(ci * w0.z); ov[quad * 8 + 3] = f2bf(ci * w0.w);
    ov[quad * 8 + 4] = f2bf(ci * w1.x); ov[quad * 8 + 5] = f2bf(ci * w1.y);
    ov[quad * 8 + 6] = f2bf(ci * w1.z); ov[quad * 8 + 7] = f2bf(ci * w1.w);
  }
  int4* dst = (int4*)(Bs + (size_t)t * 32);
  const int4* src = (const int4*)ov;
#pragma unroll
  for (int j = 0; j < 4; ++j) dst[j] = src[j];
}

// ---------------- routebuildN: Bs = exp(bij)*inv * W (iters 2,3) ------------
__global__ __launch_bounds__(256) void rbn_kernel(const float* __restrict__ W,
                                                  const float* __restrict__ bijT,
                                                  const float* __restrict__ esum,
                                                  short* __restrict__ Bs) {
  const int t = blockIdx.x * 256 + threadIdx.x;  // 0..46079
  const int kb = t / 160, n = t % 160;
  const int o = n >> 4, p = n & 15;
  const float inv = 1.0f / esum[o];
  const float4 bv = *(const float4*)(bijT + (size_t)o * IC + kb * 4);
  float cw[4];
  cw[0] = __expf(bv.x) * inv; cw[1] = __expf(bv.y) * inv;
  cw[2] = __expf(bv.z) * inv; cw[3] = __expf(bv.w) * inv;
  short ov[32];
#pragma unroll
  for (int quad = 0; quad < 4; ++quad) {
    const int i = kb * 4 + quad;
    const float ci = cw[quad];
    const float4* wp = (const float4*)(W + (((size_t)i * OD + o) * PD + p) * QD);
    const float4 w0 = wp[0], w1 = wp[1];
    ov[quad * 8 + 0] = f2bf(ci * w0.x); ov[quad * 8 + 1] = f2bf(ci * w0.y);
    ov[quad * 8 + 2] = f2bf(ci * w0.z); ov[quad * 8 + 3] = f2bf(ci * w0.w);
    ov[quad * 8 + 4] = f2bf(ci * w1.x); ov[quad * 8 + 5] = f2bf(ci * w1.y);
    ov[quad * 8 + 6] = f2bf(ci * w1.z); ov[quad * 8 + 7] = f2bf(ci * w1.w);
  }
  int4* dst = (int4*)(Bs + (size_t)t * 32);
  const int4* src = (const int4*)ov;
#pragma unroll
  for (int j = 0; j < 4; ++j) dst[j] = src[j];
}

// ---------------- sgemm: s_part[cz][b][n], A from bf16 xB -------------------
__global__ __launch_bounds__(256) void sgemm_kernel(const short* __restrict__ xB,
                                                    const short* __restrict__ Bs,
                                                    float* __restrict__ s_part) {
  const int tid = threadIdx.x;
  const int wave = tid >> 6, lane = tid & 63;
  const int ln = lane & 15, quad = lane >> 4;
  const int cz = blockIdx.x % NCS, mb = blockIdx.x / NCS;
  const int m0 = mb * 64 + wave * 16;
  f32x4 acc[10] = {};
  const short* arow = xB + (size_t)(m0 + ln) * KD + quad * 8;
#pragma unroll
  for (int step = 0; step < KSTEPS; ++step) {
    const int kb = cz * KSTEPS + step;
    const bf16x8 af = *(const bf16x8*)(arow + kb * 32);
    const short* bp = Bs + (size_t)kb * 5120 + ln * 32 + quad * 8;
#pragma unroll
    for (int nt = 0; nt < 10; ++nt) {
      const bf16x8 bf = *(const bf16x8*)(bp + nt * 512);
      acc[nt] = __builtin_amdgcn_mfma_f32_16x16x32_bf16(af, bf, acc[nt], 0, 0, 0);
    }
  }
  float* sp = s_part + (size_t)cz * SOP;
#pragma unroll
  for (int nt = 0; nt < 10; ++nt)
#pragma unroll
    for (int r = 0; r < 4; ++r)
      sp[(size_t)(m0 + quad * 4 + r) * 160 + nt * 16 + ln] = acc[nt][r];
}

// ---------------- squash: reduce + squash; emit vB (B-frag bf16) or out -----
__global__ __launch_bounds__(256) void squash_kernel(const float* __restrict__ s_part,
                                                     short* __restrict__ vB,
                                                     float* __restrict__ out,
                                                     int write_out) {
  const int t = blockIdx.x * 256 + threadIdx.x;  // < 81920, t = b*160 + n
  float sv = 0.f;
#pragma unroll 8
  for (int ch = 0; ch < NCS; ++ch) sv += s_part[(size_t)ch * SOP + t];
  float sq = sv * sv;
#pragma unroll
  for (int m = 1; m < 16; m <<= 1) sq += __shfl_xor(sq, m, 16);
  const float norm = sqrtf(sq + 1e-8f);
  const float val = sv * (sq / ((1.f + sq) * norm));
  if (write_out) {
    out[t] = val;
  } else {
    const int b = t / 160, n = t - b * 160;
    vB[((size_t)(b >> 5) * 160 + n) * 32 + (b & 31)] = f2bf(val);
  }
}

// ---------------- aggemm: bijT += agreement via MFMA; last block -> esum ----
// G[m=(i8q),(n=o*16+p)] = sum_b x[b,iq]*v[b,op]; block = (ig8, kq): 8 i x 128 b.
__global__ __launch_bounds__(256) void aggemm_kernel(const short* __restrict__ xB,
                                                     const float* __restrict__ W,
                                                     const short* __restrict__ vB,
                                                     float* __restrict__ bijT,
                                                     float* __restrict__ esum,
                                                     int* __restrict__ ctr) {
  __shared__ __align__(16) short Abuf[16 * 64 * 8];  // [mt*4+kb][lane][8] bf16, 16KB
  const int tid = threadIdx.x;
  const int ig8 = blockIdx.x, kq = blockIdx.y;
  const int b0 = kq * 128;
  // stage xB -> A-frag layout: A[m=lane&15][k=quad*8+j]  [m120-verified]
#pragma unroll
  for (int j = 0; j < 8; ++j) {
    const int idx = tid + j * 256;       // 0..2047
    const int b = idx >> 4, f4 = idx & 15;
    const bf16x4 vx = *(const bf16x4*)(xB + (size_t)(b0 + b) * KD + ig8 * 64 + f4 * 4);
    const int kb = b >> 5, qk = (b & 31) >> 3, jj = b & 7;
    const int mt2 = (f4 * 4) >> 4;
    const int mlb = (f4 & 3) * 4;
    short* dst = Abuf + (((mt2 * 4 + kb) * 64 + qk * 16 + mlb) * 8 + jj);
    dst[0] = vx[0]; dst[8] = vx[1]; dst[16] = vx[2]; dst[24] = vx[3];
  }
  __syncthreads();
  const int mt = tid >> 6, lane = tid & 63;
  const int ln = lane & 15, quad = lane >> 4;
  f32x4 acc[10] = {};
#pragma unroll
  for (int kb = 0; kb < 4; ++kb) {
    const bf16x8 af = *(const bf16x8*)(Abuf + ((mt * 4 + kb) * 64 + lane) * 8);
    const short* bp = vB + ((size_t)(kq * 4 + kb) * 160 + ln) * 32 + quad * 8;
#pragma unroll
    for (int nt = 0; nt < 10; ++nt) {
      const bf16x8 bf = *(const bf16x8*)(bp + nt * 512);
      acc[nt] = __builtin_amdgcn_mfma_f32_16x16x32_bf16(af, bf, acc[nt], 0, 0, 0);
    }
  }
  // epilogue: lane holds G[m=quad*4+r][p=ln] for o=nt; contract with W,
  // accumulate agreement directly into cumulative bijT[o][i].
  const int i = ig8 * 8 + mt * 2 + (quad >> 1);
  const int qb = (quad & 1) * 4;
#pragma unroll
  for (int nt = 0; nt < 10; ++nt) {
    const float4 wv = *(const float4*)(W + (((size_t)i * OD + nt) * PD + ln) * QD + qb);
    float pa = acc[nt][0] * wv.x + acc[nt][1] * wv.y + acc[nt][2] * wv.z + acc[nt][3] * wv.w;
    pa += __shfl_xor(pa, 1); pa += __shfl_xor(pa, 2); pa += __shfl_xor(pa, 4);
    pa += __shfl_xor(pa, 8); pa += __shfl_xor(pa, 16);
    if ((lane & 31) == 0)
      atomicAdd(&bijT[(size_t)nt * IC + i], pa * (1.0f / (float)B));
  }
  // last block computes softmax denominators (no max-subtract: |bij| ~ O(1)).
  __threadfence();
  __shared__ int lastflag;
  if (tid == 0)
    lastflag = (atomicAdd(ctr, 1) == (int)(gridDim.x * gridDim.y) - 1) ? 1 : 0;
  __syncthreads();
  if (lastflag) {
    __threadfence();  // acquire: all other blocks' bijT atomics visible
    if (tid == 0) *ctr = 0;  // reset for next aggemm dispatch / graph replay
    const int w = tid >> 6, l = tid & 63;
    for (int o = w; o < OD; o += 4) {
      float s = 0.f;
      for (int ii = l; ii < IC; ii += 64) s += __expf(bijT[(size_t)o * IC + ii]);
#pragma unroll
      for (int st = 1; st < 64; st <<= 1) s += __shfl_xor(s, st);
      if (l == 0) esum[o] = s;
    }
  }
}

// ---------------- launch: 11 dispatches --------------------------------------

extern "C" void kernel_launch(void* const* d_in, const int* in_sizes, int n_in,
                              void* d_out, int out_size, void* d_ws, size_t ws_size,
                              hipStream_t stream) {
  const float* x = (const float*)d_in[0];  // [512,1152,8] fp32
  const float* W = (const float*)d_in[1];  // [1152,10,16,8] fp32
  float* out = (float*)d_out;              // [512,10,16] fp32

  // workspace ~36 MB; every buffer written before read per call
  float* ws = (float*)d_ws;
  float* s_part = ws;                                  // 72*81920 f
  float* bijT = s_part + (size_t)NCS * SOP;            // 11520 f (cumulative bij, [o][i])
  float* esum = bijT + IO;                             // 16 f
  int* ctr = (int*)(esum + 16);                        // 16 i
  short* vB = (short*)(ctr + 16);                      // 16*160*32 shorts
  short* Bs = vB + (size_t)16 * 160 * 32;              // 288*160*32 shorts
  short* xB = Bs + (size_t)NKB * 160 * 32;             // 512*9216 shorts (bf16 x)

  const dim3 agrid(144, NCB);

  // iter 1
  prep_kernel<<<PREPX + 180, 256, 0, stream>>>(x, W, bijT, ctr, Bs, xB);
  sgemm_kernel<<<8 * NCS, 256, 0, stream>>>(xB, Bs, s_part);
  squash_kernel<<<SOP / 256, 256, 0, stream>>>(s_part, vB, out, 0);
  aggemm_kernel<<<agrid, 256, 0, stream>>>(xB, W, vB, bijT, esum, ctr);
  // iter 2
  rbn_kernel<<<180, 256, 0, stream>>>(W, bijT, esum, Bs);
  sgemm_kernel<<<8 * NCS, 256, 0, stream>>>(xB, Bs, s_part);
  squash_kernel<<<SOP / 256, 256, 0, stream>>>(s_part, vB, out, 0);
  aggemm_kernel<<<agrid, 256, 0, stream>>>(xB, W, vB, bijT, esum, ctr);
  // iter 3
  rbn_kernel<<<180, 256, 0, stream>>>(W, bijT, esum, Bs);
  sgemm_kernel<<<8 * NCS, 256, 0, stream>>>(xB, Bs, s_part);
  squash_kernel<<<SOP / 256, 256, 0, stream>>>(s_part, vB, out, 1);
}

// Round 2
// 177.739 us; speedup vs baseline: 1.4898x; 1.4898x over previous
//
#include <hip/hip_runtime.h>
#include <hip/hip_bf16.h>

// DigitCaps dynamic routing. Output fp32.
// R15: R14 minus the device-scope fence.
//  - aggemm: atomicAdd agreement into cumulative bijT, NO __threadfence / ctr /
//    last-block tail (R14's 66us aggemm stall was the agent-scope fence: L2
//    writeback+invalidate per block on non-coherent per-XCD L2s).
//  - softmax denominator (sum of exp per o; max-subtract dropped, |bij|~O(1))
//    computed redundantly per rbn block from bijT (46KB L2 reads, cheap).
//  - xB: x pre-converted to bf16 once; sgemm/aggemm A-paths read bf16.
#define B 512
#define IC 1152
#define QD 8
#define OD 10
#define PD 16
#define KD (IC * QD)       // 9216
#define NKB (KD / 32)      // 288 K32 blocks
#define NCS 72             // K-chunks for s GEMM; 288/72 = 4 K-steps
#define KSTEPS (NKB / NCS)
#define NCB 4              // b-chunks for agreement GEMM (128 each)
#define SOP (B * OD * PD)  // 81920
#define IO (IC * OD)       // 11520
#define XE (B * KD)        // 4718592 x elements
#define PREPX (XE / 8 / 256)  // 2304 blocks for xB build

typedef short bf16x8 __attribute__((ext_vector_type(8)));
typedef short bf16x4 __attribute__((ext_vector_type(4)));
typedef float f32x4 __attribute__((ext_vector_type(4)));

__device__ __forceinline__ short f2bf(float f) {
  union { float f; unsigned u; } x;
  x.f = f;
  unsigned r = x.u + 0x7FFFu + ((x.u >> 16) & 1u);  // RNE to bf16
  return (short)(r >> 16);
}

// ---------------- prep: xB build (blocks 0..2303) + Bs build mode0 ----------
__global__ __launch_bounds__(256) void prep_kernel(const float* __restrict__ x,
                                                   const float* __restrict__ W,
                                                   float* __restrict__ bijT,
                                                   short* __restrict__ Bs,
                                                   short* __restrict__ xB) {
  const int bid = blockIdx.x, tid = threadIdx.x;
  if (bid < PREPX) {
    const size_t e0 = (((size_t)bid << 8) + tid) * 8;
    const float4 a = *(const float4*)(x + e0);
    const float4 b = *(const float4*)(x + e0 + 4);
    short ov[8];
    ov[0] = f2bf(a.x); ov[1] = f2bf(a.y); ov[2] = f2bf(a.z); ov[3] = f2bf(a.w);
    ov[4] = f2bf(b.x); ov[5] = f2bf(b.y); ov[6] = f2bf(b.z); ov[7] = f2bf(b.w);
    *(int4*)(xB + e0) = *(const int4*)ov;
    return;
  }
  const int t = (bid - PREPX) * 256 + tid;  // 0..46079
  if (t < IO) bijT[t] = 0.f;                // cumulative bij zero-init
  const int kb = t / 160, n = t % 160;
  const int o = n >> 4, p = n & 15;
  const float ci = 1.0f / (float)IC;        // softmax(0) uniform
  short ov[32];
#pragma unroll
  for (int quad = 0; quad < 4; ++quad) {
    const int i = kb * 4 + quad;
    const float4* wp = (const float4*)(W + (((size_t)i * OD + o) * PD + p) * QD);
    const float4 w0 = wp[0], w1 = wp[1];
    ov[quad * 8 + 0] = f2bf(ci * w0.x); ov[quad * 8 + 1] = f2bf(ci * w0.y);
    ov[quad * 8 + 2] = f2bf(ci * w0.z); ov[quad * 8 + 3] = f2bf(ci * w0.w);
    ov[quad * 8 + 4] = f2bf(ci * w1.x); ov[quad * 8 + 5] = f2bf(ci * w1.y);
    ov[quad * 8 + 6] = f2bf(ci * w1.z); ov[quad * 8 + 7] = f2bf(ci * w1.w);
  }
  int4* dst = (int4*)(Bs + (size_t)t * 32);
  const int4* src = (const int4*)ov;
#pragma unroll
  for (int j = 0; j < 4; ++j) dst[j] = src[j];
}

// ---------------- routebuildN: esum per block + Bs = softmax(bij)*W ---------
__global__ __launch_bounds__(256) void rbn_kernel(const float* __restrict__ W,
                                                  const float* __restrict__ bijT,
                                                  short* __restrict__ Bs) {
  __shared__ float wred[4][OD];
  __shared__ float invs[OD];
  const int tid = threadIdx.x;
  const int wave = tid >> 6, lane = tid & 63;
  // per-block softmax denominators (no max-subtract: |bij| ~ O(1))
  float lsum[OD];
#pragma unroll
  for (int o = 0; o < OD; ++o) lsum[o] = 0.f;
  for (int i = tid; i < IC; i += 256) {
#pragma unroll
    for (int o = 0; o < OD; ++o) lsum[o] += __expf(bijT[(size_t)o * IC + i]);
  }
#pragma unroll
  for (int o = 0; o < OD; ++o) {
    float s = lsum[o];
#pragma unroll
    for (int st = 1; st < 64; st <<= 1) s += __shfl_xor(s, st);
    if (lane == 0) wred[wave][o] = s;
  }
  __syncthreads();
  if (tid < OD)
    invs[tid] = 1.f / (wred[0][tid] + wred[1][tid] + wred[2][tid] + wred[3][tid]);
  __syncthreads();
  // Bs build
  const int t = blockIdx.x * 256 + tid;  // 0..46079
  const int kb = t / 160, n = t % 160;
  const int o = n >> 4, p = n & 15;
  const float inv = invs[o];
  const float4 bv = *(const float4*)(bijT + (size_t)o * IC + kb * 4);
  float cw[4];
  cw[0] = __expf(bv.x) * inv; cw[1] = __expf(bv.y) * inv;
  cw[2] = __expf(bv.z) * inv; cw[3] = __expf(bv.w) * inv;
  short ov[32];
#pragma unroll
  for (int quad = 0; quad < 4; ++quad) {
    const int i = kb * 4 + quad;
    const float ci = cw[quad];
    const float4* wp = (const float4*)(W + (((size_t)i * OD + o) * PD + p) * QD);
    const float4 w0 = wp[0], w1 = wp[1];
    ov[quad * 8 + 0] = f2bf(ci * w0.x); ov[quad * 8 + 1] = f2bf(ci * w0.y);
    ov[quad * 8 + 2] = f2bf(ci * w0.z); ov[quad * 8 + 3] = f2bf(ci * w0.w);
    ov[quad * 8 + 4] = f2bf(ci * w1.x); ov[quad * 8 + 5] = f2bf(ci * w1.y);
    ov[quad * 8 + 6] = f2bf(ci * w1.z); ov[quad * 8 + 7] = f2bf(ci * w1.w);
  }
  int4* dst = (int4*)(Bs + (size_t)t * 32);
  const int4* src = (const int4*)ov;
#pragma unroll
  for (int j = 0; j < 4; ++j) dst[j] = src[j];
}

// ---------------- sgemm: s_part[cz][b][n], A from bf16 xB -------------------
__global__ __launch_bounds__(256) void sgemm_kernel(const short* __restrict__ xB,
                                                    const short* __restrict__ Bs,
                                                    float* __restrict__ s_part) {
  const int tid = threadIdx.x;
  const int wave = tid >> 6, lane = tid & 63;
  const int ln = lane & 15, quad = lane >> 4;
  const int cz = blockIdx.x % NCS, mb = blockIdx.x / NCS;
  const int m0 = mb * 64 + wave * 16;
  f32x4 acc[10] = {};
  const short* arow = xB + (size_t)(m0 + ln) * KD + quad * 8;
#pragma unroll
  for (int step = 0; step < KSTEPS; ++step) {
    const int kb = cz * KSTEPS + step;
    const bf16x8 af = *(const bf16x8*)(arow + kb * 32);
    const short* bp = Bs + (size_t)kb * 5120 + ln * 32 + quad * 8;
#pragma unroll
    for (int nt = 0; nt < 10; ++nt) {
      const bf16x8 bf = *(const bf16x8*)(bp + nt * 512);
      acc[nt] = __builtin_amdgcn_mfma_f32_16x16x32_bf16(af, bf, acc[nt], 0, 0, 0);
    }
  }
  float* sp = s_part + (size_t)cz * SOP;
#pragma unroll
  for (int nt = 0; nt < 10; ++nt)
#pragma unroll
    for (int r = 0; r < 4; ++r)
      sp[(size_t)(m0 + quad * 4 + r) * 160 + nt * 16 + ln] = acc[nt][r];
}

// ---------------- squash: reduce + squash; emit vB (B-frag bf16) or out -----
__global__ __launch_bounds__(256) void squash_kernel(const float* __restrict__ s_part,
                                                     short* __restrict__ vB,
                                                     float* __restrict__ out,
                                                     int write_out) {
  const int t = blockIdx.x * 256 + threadIdx.x;  // < 81920, t = b*160 + n
  float sv = 0.f;
#pragma unroll 8
  for (int ch = 0; ch < NCS; ++ch) sv += s_part[(size_t)ch * SOP + t];
  float sq = sv * sv;
#pragma unroll
  for (int m = 1; m < 16; m <<= 1) sq += __shfl_xor(sq, m, 16);
  const float norm = sqrtf(sq + 1e-8f);
  const float val = sv * (sq / ((1.f + sq) * norm));
  if (write_out) {
    out[t] = val;
  } else {
    const int b = t / 160, n = t - b * 160;
    vB[((size_t)(b >> 5) * 160 + n) * 32 + (b & 31)] = f2bf(val);
  }
}

// ---------------- aggemm: bijT += agreement via MFMA (no fence, no tail) ----
// G[m=(i8q),(n=o*16+p)] = sum_b x[b,iq]*v[b,op]; block = (ig8, kq): 8 i x 128 b.
__global__ __launch_bounds__(256) void aggemm_kernel(const short* __restrict__ xB,
                                                     const float* __restrict__ W,
                                                     const short* __restrict__ vB,
                                                     float* __restrict__ bijT) {
  __shared__ __align__(16) short Abuf[16 * 64 * 8];  // [mt*4+kb][lane][8] bf16, 16KB
  const int tid = threadIdx.x;
  const int ig8 = blockIdx.x, kq = blockIdx.y;
  const int b0 = kq * 128;
  // stage xB -> A-frag layout: A[m=lane&15][k=quad*8+j]  [m120-verified]
#pragma unroll
  for (int j = 0; j < 8; ++j) {
    const int idx = tid + j * 256;       // 0..2047
    const int b = idx >> 4, f4 = idx & 15;
    const bf16x4 vx = *(const bf16x4*)(xB + (size_t)(b0 + b) * KD + ig8 * 64 + f4 * 4);
    const int kb = b >> 5, qk = (b & 31) >> 3, jj = b & 7;
    const int mt2 = (f4 * 4) >> 4;
    const int mlb = (f4 & 3) * 4;
    short* dst = Abuf + (((mt2 * 4 + kb) * 64 + qk * 16 + mlb) * 8 + jj);
    dst[0] = vx[0]; dst[8] = vx[1]; dst[16] = vx[2]; dst[24] = vx[3];
  }
  __syncthreads();
  const int mt = tid >> 6, lane = tid & 63;
  const int ln = lane & 15, quad = lane >> 4;
  f32x4 acc[10] = {};
#pragma unroll
  for (int kb = 0; kb < 4; ++kb) {
    const bf16x8 af = *(const bf16x8*)(Abuf + ((mt * 4 + kb) * 64 + lane) * 8);
    const short* bp = vB + ((size_t)(kq * 4 + kb) * 160 + ln) * 32 + quad * 8;
#pragma unroll
    for (int nt = 0; nt < 10; ++nt) {
      const bf16x8 bf = *(const bf16x8*)(bp + nt * 512);
      acc[nt] = __builtin_amdgcn_mfma_f32_16x16x32_bf16(af, bf, acc[nt], 0, 0, 0);
    }
  }
  // epilogue: lane holds G[m=quad*4+r][p=ln] for o=nt; contract with W,
  // accumulate agreement directly into cumulative bijT[o][i]. Visibility to
  // the next dispatch is the kernel-boundary release — no fence needed.
  const int i = ig8 * 8 + mt * 2 + (quad >> 1);
  const int qb = (quad & 1) * 4;
#pragma unroll
  for (int nt = 0; nt < 10; ++nt) {
    const float4 wv = *(const float4*)(W + (((size_t)i * OD + nt) * PD + ln) * QD + qb);
    float pa = acc[nt][0] * wv.x + acc[nt][1] * wv.y + acc[nt][2] * wv.z + acc[nt][3] * wv.w;
    pa += __shfl_xor(pa, 1); pa += __shfl_xor(pa, 2); pa += __shfl_xor(pa, 4);
    pa += __shfl_xor(pa, 8); pa += __shfl_xor(pa, 16);
    if ((lane & 31) == 0)
      atomicAdd(&bijT[(size_t)nt * IC + i], pa * (1.0f / (float)B));
  }
}

// ---------------- launch: 11 dispatches --------------------------------------

extern "C" void kernel_launch(void* const* d_in, const int* in_sizes, int n_in,
                              void* d_out, int out_size, void* d_ws, size_t ws_size,
                              hipStream_t stream) {
  const float* x = (const float*)d_in[0];  // [512,1152,8] fp32
  const float* W = (const float*)d_in[1];  // [1152,10,16,8] fp32
  float* out = (float*)d_out;              // [512,10,16] fp32

  // workspace ~36 MB; every buffer written before read per call
  float* ws = (float*)d_ws;
  float* s_part = ws;                                  // 72*81920 f
  float* bijT = s_part + (size_t)NCS * SOP;            // 11520 f (cumulative bij, [o][i])
  short* vB = (short*)(bijT + IO);                     // 16*160*32 shorts
  short* Bs = vB + (size_t)16 * 160 * 32;              // 288*160*32 shorts
  short* xB = Bs + (size_t)NKB * 160 * 32;             // 512*9216 shorts (bf16 x)

  const dim3 agrid(144, NCB);

  // iter 1
  prep_kernel<<<PREPX + 180, 256, 0, stream>>>(x, W, bijT, Bs, xB);
  sgemm_kernel<<<8 * NCS, 256, 0, stream>>>(xB, Bs, s_part);
  squash_kernel<<<SOP / 256, 256, 0, stream>>>(s_part, vB, out, 0);
  aggemm_kernel<<<agrid, 256, 0, stream>>>(xB, W, vB, bijT);
  // iter 2
  rbn_kernel<<<180, 256, 0, stream>>>(W, bijT, Bs);
  sgemm_kernel<<<8 * NCS, 256, 0, stream>>>(xB, Bs, s_part);
  squash_kernel<<<SOP / 256, 256, 0, stream>>>(s_part, vB, out, 0);
  aggemm_kernel<<<agrid, 256, 0, stream>>>(xB, W, vB, bijT);
  // iter 3
  rbn_kernel<<<180, 256, 0, stream>>>(W, bijT, Bs);
  sgemm_kernel<<<8 * NCS, 256, 0, stream>>>(xB, Bs, s_part);
  squash_kernel<<<SOP / 256, 256, 0, stream>>>(s_part, vB, out, 1);
}